// Round 13
// baseline (326.910 us; speedup 1.0000x reference)
//
#include <hip/hip_runtime.h>
#include <hip/hip_bf16.h>
#include <cstdint>

typedef __bf16 bf16x8 __attribute__((ext_vector_type(8)));
typedef float f32x4 __attribute__((ext_vector_type(4)));
typedef float f32x16 __attribute__((ext_vector_type(16)));
typedef unsigned short u16x8 __attribute__((ext_vector_type(8)));
typedef unsigned short u16x4 __attribute__((ext_vector_type(4)));

__device__ __forceinline__ unsigned short f2bf(float f) {
  unsigned int u = __float_as_uint(f);
  u += 0x7FFFu + ((u >> 16) & 1u);
  return (unsigned short)(u >> 16);
}
__device__ __forceinline__ float bf2f(unsigned short h) {
  return __uint_as_float(((unsigned int)h) << 16);
}
__device__ __forceinline__ float frcp_(float x) { return __builtin_amdgcn_rcpf(x); }
__device__ __forceinline__ float sigmoid_fast(float x) { return frcp_(1.f + __expf(-x)); }
__device__ __forceinline__ float tanh_fast(float x) { return 1.f - 2.f * frcp_(__expf(2.f * x) + 1.f); }
__device__ __forceinline__ float siluf_(float x) { return x * sigmoid_fast(x); }

#define GLOAD_LDS16(gsrc, ldst) \
  __builtin_amdgcn_global_load_lds((const __attribute__((address_space(1))) void*)(gsrc), \
                                   (__attribute__((address_space(3))) void*)(ldst), 16, 0, 0)

#define S_BARRIER() asm volatile("s_barrier" ::: "memory")
#define LGKM0() asm volatile("s_waitcnt lgkmcnt(0)" ::: "memory")

// XCD-aware bijective tile remap (T1). Requires nwg % 8 == 0 (all our grids).
__device__ __forceinline__ void xcd_tile(int& x, int& y, int& z) {
  const int gx = gridDim.x, gy = gridDim.y;
  const int nwg = gx * gy * gridDim.z;
  const int lin = (blockIdx.z * gy + blockIdx.y) * gx + blockIdx.x;
  const int cpx = nwg >> 3;
  const int t = (lin & 7) * cpx + (lin >> 3);
  x = t % gx;
  const int r = t / gx;
  y = r % gy;
  z = r / gy;
}

// ---------------------------------------------------------------------------
// GEMM core v8 — v7 structure with 32x32x16 MFMA (m119: 2495 vs 2176 TF pipe
// ceiling, +15-21% FLOP/busy-cycle; half the MFMA issue slots).
// Block: 256 thr / 4 waves (2M x 2N), tile 128(M) x 256(N), BK=32.
// Wave output 64x128 = 2x4 frags of 32x32; acc = 8 x f32x16 = 128 VGPR.
// Per K-step 2 symmetric phases (k-half 0 / 1), each:
//   {6 ds_read (A2+B4); stage(T+2); [vmcnt gate at p1]; BARRIER; lgkm0;
//    setprio(1); 8 MFMA; setprio(0)}
// Operand layout 32x32x16: lane l holds row l&31, k=(l>>5)*8+e (16B at byte
// row*64 + khalf*32 + (l>>5)*16). C/D: col=lane&31, row=(reg&3)+8*(reg>>2)
// +4*(lane>>5)  [m74/m101 verified].
// LDS layout/staging/swizzle identical to v7 (3 bufs x 24KB, 2-tile
// lookahead, steady vmcnt(6), swizzle o^=((o>>7)&3)<<4 both sides).
// ---------------------------------------------------------------------------
template<int F32>
__device__ __forceinline__ void gemm4_core(
    const unsigned short* __restrict__ A1, int lda1, int K1,
    const unsigned short* __restrict__ A2, int lda2, int K2,
    const unsigned short* __restrict__ Bt, int ldb,
    void* __restrict__ C, int ldc,
    int tm, int tn, unsigned short* lds)
{
  const int tid = threadIdx.x;
  const int lane = tid & 63;
  const int wave = tid >> 6;                 // 0..3
  const int wm = (wave >> 1) * 64;           // 0 / 64
  const int wn = (wave & 1) * 128;           // 0 / 128
  const int frow = lane & 31;
  const int kc16 = (lane >> 5) * 16;         // byte offset of k-subchunk
  const int nt = (K1 + K2) >> 5;

  // buffer layout (24KB): A 128x32 @0 (8KB), B 256x32 @+4096 elem (16KB)
  auto stageA = [&](unsigned short* buf, int ktBase) {
    const unsigned short* Ab; int alda, kloc;
    if (ktBase >= K1) { Ab = A2; alda = lda2; kloc = ktBase - K1; }
    else              { Ab = A1; alda = lda1; kloc = ktBase; }
#pragma unroll
    for (int j = 0; j < 2; ++j) {
      int o = j * 4096 + tid * 16;
      int so = o ^ (((o >> 7) & 3) << 4);
      int row = so >> 6, cb = so & 63;
      GLOAD_LDS16(Ab + (long long)(tm + row) * alda + kloc + (cb >> 1),
                  (char*)buf + j * 4096 + wave * 1024);
    }
  };
  auto stageB = [&](unsigned short* buf, int ktBase) {
    char* bb = (char*)buf + 8192;
#pragma unroll
    for (int j = 0; j < 4; ++j) {
      int o = j * 4096 + tid * 16;
      int so = o ^ (((o >> 7) & 3) << 4);
      int row = so >> 6, cb = so & 63;
      GLOAD_LDS16(Bt + (long long)(tn + row) * ldb + ktBase + (cb >> 1),
                  bb + j * 4096 + wave * 1024);
    }
  };
  auto ldswz = [&](const unsigned short* rg, int row, int khalf) -> bf16x8 {
    int o = row * 64 + khalf * 32 + kc16;
    o ^= ((o >> 7) & 3) << 4;
    return *(const bf16x8*)((const char*)rg + o);
  };

  f32x16 acc[2][4] = {};

  unsigned short* pc = lds;
  unsigned short* pn = lds + 12288;
  unsigned short* pf = lds + 24576;

  stageA(pc, 0); stageB(pc, 0);
  stageA(pn, 32); stageB(pn, 32);
  asm volatile("s_waitcnt vmcnt(6)" ::: "memory");
  S_BARRIER();

  for (int T = 0; T < nt; ++T) {
    // ---- phase 0 (k-half 0) ----
    bf16x8 av[2], bv[4];
#pragma unroll
    for (int i = 0; i < 2; ++i) av[i] = ldswz(pc, wm + i * 32 + frow, 0);
#pragma unroll
    for (int j = 0; j < 4; ++j) bv[j] = ldswz(pc + 4096, wn + j * 32 + frow, 0);
    if (T + 2 < nt) stageA(pf, (T + 2) * 32);
    S_BARRIER();
    LGKM0();
    __builtin_amdgcn_s_setprio(1);
#pragma unroll
    for (int i = 0; i < 2; ++i)
#pragma unroll
      for (int j = 0; j < 4; ++j)
        acc[i][j] = __builtin_amdgcn_mfma_f32_32x32x16_bf16(av[i], bv[j], acc[i][j], 0, 0, 0);
    __builtin_amdgcn_s_setprio(0);
    // ---- phase 1 (k-half 1) ----
    bf16x8 a2[2], b2[4];
#pragma unroll
    for (int i = 0; i < 2; ++i) a2[i] = ldswz(pc, wm + i * 32 + frow, 1);
#pragma unroll
    for (int j = 0; j < 4; ++j) b2[j] = ldswz(pc + 4096, wn + j * 32 + frow, 1);
    if (T + 2 < nt) {
      stageB(pf, (T + 2) * 32);
      if (T + 1 < nt) asm volatile("s_waitcnt vmcnt(6)" ::: "memory");
    } else if (T + 1 < nt) {
      asm volatile("s_waitcnt vmcnt(0)" ::: "memory");
    }
    S_BARRIER();
    LGKM0();
    __builtin_amdgcn_s_setprio(1);
#pragma unroll
    for (int i = 0; i < 2; ++i)
#pragma unroll
      for (int j = 0; j < 4; ++j)
        acc[i][j] = __builtin_amdgcn_mfma_f32_32x32x16_bf16(a2[i], b2[j], acc[i][j], 0, 0, 0);
    __builtin_amdgcn_s_setprio(0);
    unsigned short* t = pc; pc = pn; pn = pf; pf = t;
  }

  // C-write: col=lane&31, row=(reg&3)+8*(reg>>2)+4*(lane>>5)
  const int cc = lane & 31;
  const int rb = (lane >> 5) * 4;
#pragma unroll
  for (int fi = 0; fi < 2; ++fi)
#pragma unroll
    for (int fj = 0; fj < 4; ++fj) {
      const int col = tn + wn + fj * 32 + cc;
#pragma unroll
      for (int reg = 0; reg < 16; ++reg) {
        const int row = tm + wm + fi * 32 + (reg & 3) + 8 * (reg >> 2) + rb;
        if (F32) ((float*)C)[(long long)row * ldc + col] = acc[fi][fj][reg];
        else ((unsigned short*)C)[(long long)row * ldc + col] = f2bf(acc[fi][fj][reg]);
      }
    }
}

// Batched (z = group) two-segment GEMM, bf16 output. XCD-swizzled tiles.
__global__ __launch_bounds__(256, 2) void gemm4(
    const unsigned short* __restrict__ A1, int lda1, long long a1_bs, int K1,
    const unsigned short* __restrict__ A2, int lda2, int K2,
    const unsigned short* __restrict__ Bt, int ldb, long long bt_bs,
    unsigned short* __restrict__ C, int ldc, long long c_bs)
{
  __shared__ unsigned short lds[3 * 12288];   // 72 KB
  int tx, ty, g;
  xcd_tile(tx, ty, g);
  gemm4_core<0>(A1 + (long long)g * a1_bs, lda1, K1, A2, lda2, K2,
                Bt + (long long)g * bt_bs, ldb,
                C + (long long)g * c_bs, ldc,
                ty * 128, tx * 256, lds);
}

// Branch pack: z selects one of 8 configs (7x split-K of branch0 + branch1).
struct BCfg { const unsigned short* A; int lda; int K;
              const unsigned short* Bt; int ldb; unsigned short* C; };
struct BPack { BCfg c[8]; };
__global__ __launch_bounds__(256, 2) void gemm4_branch(BPack p) {
  __shared__ unsigned short lds[3 * 12288];
  int tx, ty, z;
  xcd_tile(tx, ty, z);
  BCfg c = p.c[z];
  gemm4_core<0>(c.A, c.lda, c.K, nullptr, 0, 0, c.Bt, c.ldb, c.C, 512,
                ty * 128, tx * 256, lds);
}

// ---------------------------------------------------------------------------
// Fused gates GEMM + GRU combine, v8 (32x32x16). Tile 128M x 192N(nn),
// 4 waves (2M x 2 o-blocks), wave = 64 x 96 = 2x3 frags of 32x32.
// Wgt pre-permuted 32-granular: nn = (o>>5)*96 + gate*32 + (o&31) ->
// B-frag fj IS gate fj for o-block (wave&1); acc[2][3] f32x16 = 96 VGPR.
// Buffer 20KB: A 128x32 @0, B 192x32 @+4096 elem; steady vmcnt(5).
// ---------------------------------------------------------------------------
__global__ __launch_bounds__(256, 2) void gemm_gru(
    const unsigned short* __restrict__ hB,
    const unsigned short* __restrict__ Wgt,
    const float* __restrict__ bg,
    const unsigned short* __restrict__ deterB,
    float* __restrict__ out)
{
  __shared__ unsigned short lds[3 * 10240];   // 60 KB
  int txi, tyi, g;
  xcd_tile(txi, tyi, g);
  const int tm = tyi * 128;
  const int tn = txi * 192;
  const unsigned short* A  = hB + g * 512;
  const unsigned short* Bt = Wgt + (long long)g * 1536 * 512;
  const int tid = threadIdx.x, lane = tid & 63, wave = tid >> 6;
  const int wm = (wave >> 1) * 64;
  const int w1 = wave & 1;                    // o-block within tile
  const int frow = lane & 31;
  const int kc16 = (lane >> 5) * 16;
  const int nt = 16;                          // K=512

  auto stageA = [&](unsigned short* buf, int kt) {
#pragma unroll
    for (int j = 0; j < 2; ++j) {
      int o = j * 4096 + tid * 16;
      int so = o ^ (((o >> 7) & 3) << 4);
      int row = so >> 6, cb = so & 63;
      GLOAD_LDS16(A + (long long)(tm + row) * 4096 + kt + (cb >> 1),
                  (char*)buf + j * 4096 + wave * 1024);
    }
  };
  auto stageB = [&](unsigned short* buf, int kt) {
    char* bb = (char*)buf + 8192;
#pragma unroll
    for (int j = 0; j < 3; ++j) {
      int o = j * 4096 + tid * 16;
      int so = o ^ (((o >> 7) & 3) << 4);
      int row = so >> 6, cb = so & 63;
      GLOAD_LDS16(Bt + (long long)(tn + row) * 512 + kt + (cb >> 1),
                  bb + j * 4096 + wave * 1024);
    }
  };
  auto ldA = [&](const unsigned short* buf, int fi, int khalf) -> bf16x8 {
    int o = (wm + fi * 32 + frow) * 64 + khalf * 32 + kc16;
    o ^= ((o >> 7) & 3) << 4;
    return *(const bf16x8*)((const char*)buf + o);
  };
  auto ldB = [&](const unsigned short* buf, int gate, int khalf) -> bf16x8 {
    int row = w1 * 96 + gate * 32 + frow;
    int o = row * 64 + khalf * 32 + kc16;
    o ^= ((o >> 7) & 3) << 4;
    return *(const bf16x8*)((const char*)buf + 8192 + o);
  };

  f32x16 acc[2][3] = {};

  unsigned short* pc = lds;
  unsigned short* pn = lds + 10240;
  unsigned short* pf = lds + 20480;

  stageA(pc, 0); stageB(pc, 0);
  stageA(pn, 32); stageB(pn, 32);
  asm volatile("s_waitcnt vmcnt(5)" ::: "memory");
  S_BARRIER();

  for (int T = 0; T < nt; ++T) {
    // phase 0 (k-half 0)
    bf16x8 av[2], bv[3];
#pragma unroll
    for (int i = 0; i < 2; ++i) av[i] = ldA(pc, i, 0);
#pragma unroll
    for (int j = 0; j < 3; ++j) bv[j] = ldB(pc, j, 0);
    if (T + 2 < nt) stageA(pf, (T + 2) * 32);
    S_BARRIER();
    LGKM0();
    __builtin_amdgcn_s_setprio(1);
#pragma unroll
    for (int i = 0; i < 2; ++i)
#pragma unroll
      for (int j = 0; j < 3; ++j)
        acc[i][j] = __builtin_amdgcn_mfma_f32_32x32x16_bf16(av[i], bv[j], acc[i][j], 0, 0, 0);
    __builtin_amdgcn_s_setprio(0);
    // phase 1 (k-half 1)
    bf16x8 a2[2], b2[3];
#pragma unroll
    for (int i = 0; i < 2; ++i) a2[i] = ldA(pc, i, 1);
#pragma unroll
    for (int j = 0; j < 3; ++j) b2[j] = ldB(pc, j, 1);
    if (T + 2 < nt) {
      stageB(pf, (T + 2) * 32);
      if (T + 1 < nt) asm volatile("s_waitcnt vmcnt(5)" ::: "memory");
    } else if (T + 1 < nt) {
      asm volatile("s_waitcnt vmcnt(0)" ::: "memory");
    }
    S_BARRIER();
    LGKM0();
    __builtin_amdgcn_s_setprio(1);
#pragma unroll
    for (int i = 0; i < 2; ++i)
#pragma unroll
      for (int j = 0; j < 3; ++j)
        acc[i][j] = __builtin_amdgcn_mfma_f32_32x32x16_bf16(a2[i], b2[j], acc[i][j], 0, 0, 0);
    __builtin_amdgcn_s_setprio(0);
    unsigned short* t = pc; pc = pn; pn = pf; pf = t;
  }

  // GRU epilogue: frag fj = gate; o_col = txi*64 + w1*32 + (lane&31)
  const int cc = lane & 31;
  const int rb = (lane >> 5) * 4;
  const int o_col = txi * 64 + w1 * 32 + cc;
  const int gcol = g * 512 + o_col;
  const float bgr = bg[g * 1536 + o_col];
  const float bgc = bg[g * 1536 + 512 + o_col];
  const float bgu = bg[g * 1536 + 1024 + o_col];
#pragma unroll
  for (int fi = 0; fi < 2; ++fi) {
#pragma unroll
    for (int reg = 0; reg < 16; ++reg) {
      const int row = tm + wm + fi * 32 + (reg & 3) + 8 * (reg >> 2) + rb;
      const long long off = (long long)row * 4096 + gcol;
      float dt = bf2f(deterB[off]);
      float reset = sigmoid_fast(acc[fi][0][reg] + bgr);
      float cand  = tanh_fast(reset * (acc[fi][1][reg] + bgc));
      float upd   = sigmoid_fast(acc[fi][2][reg] + bgu - 1.f);
      out[off] = upd * cand + (1.f - upd) * dt;
    }
  }
}

// ---------------------------------------------------------------------------
// Merged preprocessing: fp32->bf16 casts + all weight transposes, one launch.
// ---------------------------------------------------------------------------
__device__ __forceinline__ void transpose_dev(
    const float* __restrict__ src, unsigned short* __restrict__ dst,
    int R, int C, int bx, int by, int bz, float (*t)[132])
{
  const long long bOff = (long long)bz * R * C;
  src += bOff; dst += bOff;
  const int c0 = bx * 128, r0 = by * 32;
  const int tid = threadIdx.x;
  const int tx = tid & 31, ty = tid >> 5;
#pragma unroll
  for (int j = 0; j < 4; ++j) {
    int row = ty + j * 8;
    float4 v = *(const float4*)&src[(long long)(r0 + row) * C + c0 + tx * 4];
    *(float4*)&t[row][tx * 4] = v;
  }
  __syncthreads();
#pragma unroll
  for (int j = 0; j < 4; ++j) {
    int idx = j * 256 + tid;
    int c = idx >> 3, rg = idx & 7;
    u16x4 o;
    o.x = f2bf(t[rg * 4 + 0][c]); o.y = f2bf(t[rg * 4 + 1][c]);
    o.z = f2bf(t[rg * 4 + 2][c]); o.w = f2bf(t[rg * 4 + 3][c]);
    *(u16x4*)&dst[(long long)(c0 + c) * R + r0 + rg * 4] = o;
  }
}

__device__ __forceinline__ void transpose_wg_dev(
    const float* __restrict__ src, unsigned short* __restrict__ dst,
    int bx, int by, int bz, float (*t)[132])
{
  src += (long long)bz * 512 * 1536;
  dst += (long long)bz * 1536 * 512;
  const int c0 = bx * 128, r0 = by * 32;
  const int tid = threadIdx.x;
  const int tx = tid & 31, ty = tid >> 5;
#pragma unroll
  for (int j = 0; j < 4; ++j) {
    int row = ty + j * 8;
    float4 v = *(const float4*)&src[(long long)(r0 + row) * 1536 + c0 + tx * 4];
    *(float4*)&t[row][tx * 4] = v;
  }
  __syncthreads();
#pragma unroll
  for (int j = 0; j < 4; ++j) {
    int idx = j * 256 + tid;
    int c = idx >> 3, rg = idx & 7;
    int cc = c0 + c;
    int gate = cc >> 9, o = cc & 511;
    int nn = (o >> 5) * 96 + gate * 32 + (o & 31);   // 32-granular gate stripes
    u16x4 oo;
    oo.x = f2bf(t[rg * 4 + 0][c]); oo.y = f2bf(t[rg * 4 + 1][c]);
    oo.z = f2bf(t[rg * 4 + 2][c]); oo.w = f2bf(t[rg * 4 + 3][c]);
    *(u16x4*)&dst[(long long)nn * 512 + r0 + rg * 4] = oo;
  }
}

__global__ __launch_bounds__(256) void preproc_k(
    const float* __restrict__ deter, unsigned short* __restrict__ deterB,
    const float* __restrict__ stoch, unsigned short* __restrict__ stochB,
    const float* __restrict__ W0, unsigned short* __restrict__ W0t,
    const float* __restrict__ W1, unsigned short* __restrict__ W1t,
    const float* __restrict__ Wh0, unsigned short* __restrict__ Wh0t,
    const float* __restrict__ Wh1, unsigned short* __restrict__ Wh1t,
    const float* __restrict__ Wg, unsigned short* __restrict__ Wgt)
{
  __shared__ float t[32][132];
  int b = blockIdx.x;
  if (b < 20480) {
    int i = b * 256 + threadIdx.x;
    const float* s; unsigned short* d;
    if (i < 4194304) { s = deter; d = deterB; }
    else { i -= 4194304; if (i >= 1048576) return; s = stoch; d = stochB; }
    float4 v = ((const float4*)s)[i];
    u16x4 o;
    o.x = f2bf(v.x); o.y = f2bf(v.y); o.z = f2bf(v.z); o.w = f2bf(v.w);
    ((u16x4*)d)[i] = o;
    return;
  }
  b -= 20480;
  if (b < 512)  { transpose_dev(W0, W0t, 4096, 512, b & 3, b >> 2, 0, t); return; }
  b -= 512;
  if (b < 128)  { transpose_dev(W1, W1t, 1024, 512, b & 3, b >> 2, 0, t); return; }
  b -= 128;
  if (b < 2560) { transpose_dev(Wh0, Wh0t, 2560, 512, b & 3, (b >> 2) % 80, b / 320, t); return; }
  b -= 2560;
  if (b < 512)  { transpose_dev(Wh1, Wh1t, 512, 512, b & 3, (b >> 2) & 15, b >> 6, t); return; }
  b -= 512;
  transpose_wg_dev(Wg, Wgt, b % 12, (b / 12) & 15, b / 192, t);
}

// ---------------------------------------------------------------------------
// Merged branch epilogues. blockIdx.y: 0 -> branch0 (sum 7 bf16 split-K
// partials), 1 -> branch1, 2/3 -> branch2/3 (tiny-K fp32 GEMM).
// All: +bias -> RMSNorm(512) -> SiLU -> x (bf16).
// ---------------------------------------------------------------------------
__global__ __launch_bounds__(256) void branch_epi_k(
    const unsigned short* __restrict__ yP0b, const unsigned short* __restrict__ yP1b,
    const float* __restrict__ b0, const float* __restrict__ g0,
    const float* __restrict__ b1, const float* __restrict__ g1,
    const float* __restrict__ action, const float* __restrict__ demb,
    const float* __restrict__ W2, const float* __restrict__ b2, const float* __restrict__ g2,
    const float* __restrict__ W3, const float* __restrict__ b3, const float* __restrict__ g3,
    unsigned short* __restrict__ x)
{
  const int row = blockIdx.x, br = blockIdx.y;
  const int tid = threadIdx.x, lane = tid & 63, wave = tid >> 6;
  __shared__ float red[4];
  __shared__ float a[32];
  float v0, v1;
  const float* gg;
  if (br == 0) {
    const unsigned short* p = yP0b + (long long)row * 512;
    v0 = b0[tid]; v1 = b0[tid + 256];
#pragma unroll
    for (int c = 0; c < 7; ++c) {
      v0 += bf2f(p[(long long)c * 2097152 + tid]);
      v1 += bf2f(p[(long long)c * 2097152 + tid + 256]);
    }
    gg = g0;
  } else if (br == 1) {
    const unsigned short* p = yP1b + (long long)row * 512;
    v0 = b1[tid] + bf2f(p[tid]);
    v1 = b1[tid + 256] + bf2f(p[tid + 256]);
    gg = g1;
  } else {
    const int K = (br == 3) ? 16 : 32;
    const float* W  = (br == 3) ? W3 : W2;
    const float* bb = (br == 3) ? b3 : b2;
    gg = (br == 3) ? g3 : g2;
    if (tid < K) {
      float t = (br == 3) ? demb[(long long)row * 16 + tid]
                          : action[(long long)row * 32 + tid];
      if (br == 2) t = t / fmaxf(fabsf(t), 1.f);
      a[tid] = t;
    }
    __syncthreads();
    v0 = bb[tid]; v1 = bb[tid + 256];
    for (int k = 0; k < K; ++k) {
      float av = a[k];
      v0 += av * W[k * 512 + tid];
      v1 += av * W[k * 512 + tid + 256];
    }
  }
  float ss = v0 * v0 + v1 * v1;
  for (int o = 32; o > 0; o >>= 1) ss += __shfl_xor(ss, o);
  if (lane == 0) red[wave] = ss;
  __syncthreads();
  float ms = (red[0] + red[1] + red[2] + red[3]) * (1.f / 512.f);
  float sc = rsqrtf(ms + 1e-4f);
  unsigned short* xr = x + (long long)row * 2048 + br * 512;
  xr[tid]       = f2bf(siluf_(v0 * sc * gg[tid]));
  xr[tid + 256] = f2bf(siluf_(v1 * sc * gg[tid + 256]));
}

// ---------------------------------------------------------------------------
// Full-width (4096) epilogue: y(bf16) + bias -> RMSNorm -> SiLU -> h(bf16).
// ---------------------------------------------------------------------------
__global__ __launch_bounds__(256) void epi_full_k(
    const unsigned short* __restrict__ y, const float* __restrict__ bias,
    const float* __restrict__ gw, unsigned short* __restrict__ h)
{
  const int row = blockIdx.x;
  __shared__ float red[4];
  const int tid = threadIdx.x, lane = tid & 63, wave = tid >> 6;
  const u16x8* yv = (const u16x8*)(y + (long long)row * 4096);
  u16x8 ta = yv[tid], tb = yv[256 + tid];
  float ba[8], bb8[8];
  *(float4*)&ba[0]  = *(const float4*)&bias[tid * 8];
  *(float4*)&ba[4]  = *(const float4*)&bias[tid * 8 + 4];
  *(float4*)&bb8[0] = *(const float4*)&bias[(256 + tid) * 8];
  *(float4*)&bb8[4] = *(const float4*)&bias[(256 + tid) * 8 + 4];
  float fa[8], fb[8];
  float ss = 0.f;
#pragma unroll
  for (int e = 0; e < 8; ++e) {
    fa[e] = bf2f(ta[e]) + ba[e];  ss += fa[e] * fa[e];
    fb[e] = bf2f(tb[e]) + bb8[e]; ss += fb[e] * fb[e];
  }
  for (int o = 32; o > 0; o >>= 1) ss += __shfl_xor(ss, o);
  if (lane == 0) red[wave] = ss;
  __syncthreads();
  float ms = (red[0] + red[1] + red[2] + red[3]) * (1.f / 4096.f);
  float sc = rsqrtf(ms + 1e-4f);
  float ga[8], gb8[8];
  *(float4*)&ga[0]  = *(const float4*)&gw[tid * 8];
  *(float4*)&ga[4]  = *(const float4*)&gw[tid * 8 + 4];
  *(float4*)&gb8[0] = *(const float4*)&gw[(256 + tid) * 8];
  *(float4*)&gb8[4] = *(const float4*)&gw[(256 + tid) * 8 + 4];
  u16x8 oa, ob;
#pragma unroll
  for (int e = 0; e < 8; ++e) {
    oa[e] = f2bf(siluf_(fa[e] * sc * ga[e]));
    ob[e] = f2bf(siluf_(fb[e] * sc * gb8[e]));
  }
  u16x8* hv = (u16x8*)(h + (long long)row * 4096);
  hv[tid] = oa;
  hv[256 + tid] = ob;
}

// ---------------------------------------------------------------------------
extern "C" void kernel_launch(void* const* d_in, const int* in_sizes, int n_in,
                              void* d_out, int out_size, void* d_ws, size_t ws_size,
                              hipStream_t stream) {
  const float* stoch  = (const float*)d_in[0];
  const float* deter  = (const float*)d_in[1];
  const float* action = (const float*)d_in[2];
  const float* demb   = (const float*)d_in[3];
  const float* W0 = (const float*)d_in[4];
  const float* b0 = (const float*)d_in[5];
  const float* g0 = (const float*)d_in[6];
  const float* W1 = (const float*)d_in[7];
  const float* b1 = (const float*)d_in[8];
  const float* g1 = (const float*)d_in[9];
  const float* W2 = (const float*)d_in[10];
  const float* b2 = (const float*)d_in[11];
  const float* g2 = (const float*)d_in[12];
  const float* W3 = (const float*)d_in[13];
  const float* b3 = (const float*)d_in[14];
  const float* g3 = (const float*)d_in[15];
  const float* Wh0 = (const float*)d_in[16];
  const float* bh0 = (const float*)d_in[17];
  const float* gh0 = (const float*)d_in[18];
  const float* Wh1 = (const float*)d_in[19];
  const float* bh1 = (const float*)d_in[20];
  const float* gh1 = (const float*)d_in[21];
  const float* Wg  = (const float*)d_in[22];
  const float* bg  = (const float*)d_in[23];
  float* out = (float*)d_out;

  char* ws = (char*)d_ws;
  unsigned short* deterB = (unsigned short*)(ws + 0);          // 33.55 MB, whole run
  unsigned short* stochB = (unsigned short*)(ws + 33554432);   //  8.39 MB
  unsigned short* W0t    = (unsigned short*)(ws + 41943040);   //  4.19 MB
  unsigned short* W1t    = (unsigned short*)(ws + 46137344);   //  1.05 MB
  unsigned short* xB     = (unsigned short*)(ws + 47185920);   // 16.78 MB
  unsigned short* yP0b   = (unsigned short*)(ws + 63963136);   // 29.36 MB: 7 bf16 partials (early)
  unsigned short* yB     = (unsigned short*)(ws + 63963136);   // 33.55 MB (late)
  unsigned short* yP1b   = (unsigned short*)(ws + 97517568);   //  4.19 MB bf16 partial
  unsigned short* Wh0t   = (unsigned short*)(ws + 105906176);  // 20.97 MB
  unsigned short* Wh1t   = (unsigned short*)(ws + 126877696);  //  4.19 MB
  unsigned short* hB     = (unsigned short*)(ws + 134217728);  // 33.55 MB
  unsigned short* Wgt    = (unsigned short*)(ws + 167772160);  // 12.58 MB -> ends 180.4 MB
  (void)in_sizes; (void)n_in; (void)out_size; (void)ws_size;

  dim3 b256(256);
  // all preprocessing in one launch (casts + 5 transposes)
  preproc_k<<<dim3(25728), b256, 0, stream>>>(deter, deterB, stoch, stochB,
                                              W0, W0t, W1, W1t, Wh0, Wh0t,
                                              Wh1, Wh1t, Wg, Wgt);
  // branches 0+1: split-K x7 for branch0 (640 + 6x576) + branch1 (K=1024).
  // Grid 512 wg = exactly 2 blocks/CU, single round.
  {
    const int k0s[7]  = {0, 640, 1216, 1792, 2368, 2944, 3520};
    const int klen[7] = {640, 576, 576, 576, 576, 576, 576};
    BPack p;
    for (int z = 0; z < 7; ++z)
      p.c[z] = { deterB + k0s[z], 4096, klen[z], W0t + k0s[z], 4096,
                 yP0b + (long long)z * 2097152 };
    p.c[7] = { stochB, 1024, 1024, W1t, 1024, yP1b };
    gemm4_branch<<<dim3(2, 32, 8), b256, 0, stream>>>(p);
  }
  // all four branch epilogues in one launch
  branch_epi_k<<<dim3(4096, 4), b256, 0, stream>>>(yP0b, yP1b, b0, g0, b1, g1,
                                                   action, demb, W2, b2, g2, W3, b3, g3, xB);
  // hidden block layer 0: [deter_blk | x] @ Wh0  (512 wg, single round)
  gemm4<<<dim3(2, 32, 8), b256, 0, stream>>>(deterB, 4096, 512, 512, xB, 2048, 2048,
                                             Wh0t, 2560, 512LL * 2560, yB, 4096, 512);
  epi_full_k<<<dim3(4096), b256, 0, stream>>>(yB, bh0, gh0, hB);
  // hidden block layer 1  (512 wg, single round)
  gemm4<<<dim3(2, 32, 8), b256, 0, stream>>>(hB, 4096, 512, 512, nullptr, 0, 0,
                                             Wh1t, 512, 512LL * 512, yB, 4096, 512);
  epi_full_k<<<dim3(4096), b256, 0, stream>>>(yB, bh1, gh1, hB);
  // fused gates GEMM + GRU combine -> out (fp32); 2048 wg = 4 exact rounds
  gemm_gru<<<dim3(8, 32, 8), b256, 0, stream>>>(hB, Wgt, bg, deterB, out);
}

// Round 15
// 317.061 us; speedup vs baseline: 1.0311x; 1.0311x over previous
//
#include <hip/hip_runtime.h>
#include <hip/hip_bf16.h>
#include <cstdint>

typedef __bf16 bf16x8 __attribute__((ext_vector_type(8)));
typedef float f32x4 __attribute__((ext_vector_type(4)));
typedef unsigned short u16x8 __attribute__((ext_vector_type(8)));
typedef unsigned short u16x4 __attribute__((ext_vector_type(4)));

__device__ __forceinline__ unsigned short f2bf(float f) {
  unsigned int u = __float_as_uint(f);
  u += 0x7FFFu + ((u >> 16) & 1u);
  return (unsigned short)(u >> 16);
}
__device__ __forceinline__ float bf2f(unsigned short h) {
  return __uint_as_float(((unsigned int)h) << 16);
}
__device__ __forceinline__ float frcp_(float x) { return __builtin_amdgcn_rcpf(x); }
__device__ __forceinline__ float sigmoid_fast(float x) { return frcp_(1.f + __expf(-x)); }
__device__ __forceinline__ float tanh_fast(float x) { return 1.f - 2.f * frcp_(__expf(2.f * x) + 1.f); }
__device__ __forceinline__ float siluf_(float x) { return x * sigmoid_fast(x); }

#define GLOAD_LDS16(gsrc, ldst) \
  __builtin_amdgcn_global_load_lds((const __attribute__((address_space(1))) void*)(gsrc), \
                                   (__attribute__((address_space(3))) void*)(ldst), 16, 0, 0)

#define S_BARRIER() asm volatile("s_barrier" ::: "memory")
#define LGKM0() asm volatile("s_waitcnt lgkmcnt(0)" ::: "memory")

// XCD-aware bijective tile remap (T1). Requires nwg % 8 == 0 (all our grids).
__device__ __forceinline__ void xcd_tile(int& x, int& y, int& z) {
  const int gx = gridDim.x, gy = gridDim.y;
  const int nwg = gx * gy * gridDim.z;
  const int lin = (blockIdx.z * gy + blockIdx.y) * gx + blockIdx.x;
  const int cpx = nwg >> 3;
  const int t = (lin & 7) * cpx + (lin >> 3);
  x = t % gx;
  const int r = t / gx;
  y = r % gy;
  z = r / gy;
}

// ---------------------------------------------------------------------------
// GEMM core v7 — phase-converged 2-phase/BK32 schedule, 2 blocks/CU.
// Block: 256 thr / 4 waves (2M x 2N), tile 128(M) x 256(N), BK=32.
// 3 LDS buffers x 24KB = 72KB, 2-tile lookahead, steady vmcnt(6),
// swizzle o^=((o>>7)&3)<<4 on both stage source coords and ds_read addrs
// (zero measured bank conflicts).
// ---------------------------------------------------------------------------
template<int F32>
__device__ __forceinline__ void gemm4_core(
    const unsigned short* __restrict__ A1, int lda1, int K1,
    const unsigned short* __restrict__ A2, int lda2, int K2,
    const unsigned short* __restrict__ Bt, int ldb,
    void* __restrict__ C, int ldc,
    int tm, int tn, unsigned short* lds)
{
  const int tid = threadIdx.x;
  const int lane = tid & 63;
  const int wave = tid >> 6;                 // 0..3
  const int wm = (wave >> 1) * 64;           // 0 / 64
  const int wn = (wave & 1) * 128;           // 0 / 128
  const int frow = lane & 15;
  const int chunk16 = (lane >> 4) * 16;
  const int nt = (K1 + K2) >> 5;

  // buffer layout (24KB): A 128x32 @0 (8KB), B 256x32 @8192 (16KB)
  auto stageA = [&](unsigned short* buf, int ktBase) {
    const unsigned short* Ab; int alda, kloc;
    if (ktBase >= K1) { Ab = A2; alda = lda2; kloc = ktBase - K1; }
    else              { Ab = A1; alda = lda1; kloc = ktBase; }
#pragma unroll
    for (int j = 0; j < 2; ++j) {
      int o = j * 4096 + tid * 16;
      int so = o ^ (((o >> 7) & 3) << 4);
      int row = so >> 6, cb = so & 63;
      GLOAD_LDS16(Ab + (long long)(tm + row) * alda + kloc + (cb >> 1),
                  (char*)buf + j * 4096 + wave * 1024);
    }
  };
  auto stageB = [&](unsigned short* buf, int ktBase) {
    char* bb = (char*)buf + 8192;
#pragma unroll
    for (int j = 0; j < 4; ++j) {
      int o = j * 4096 + tid * 16;
      int so = o ^ (((o >> 7) & 3) << 4);
      int row = so >> 6, cb = so & 63;
      GLOAD_LDS16(Bt + (long long)(tn + row) * ldb + ktBase + (cb >> 1),
                  bb + j * 4096 + wave * 1024);
    }
  };
  auto ldswz = [&](const unsigned short* rg, int row) -> bf16x8 {
    int o = row * 64 + chunk16;
    o ^= ((o >> 7) & 3) << 4;
    return *(const bf16x8*)((const char*)rg + o);
  };

  f32x4 acc[4][8] = {};

  unsigned short* pc = lds;
  unsigned short* pn = lds + 12288;
  unsigned short* pf = lds + 24576;

  // prologue: stage tiles 0,1 (12 loads); vmcnt(6) -> tile0 landed.
  stageA(pc, 0); stageB(pc, 0);
  stageA(pn, 32); stageB(pn, 32);
  asm volatile("s_waitcnt vmcnt(6)" ::: "memory");
  S_BARRIER();

  for (int T = 0; T < nt; ++T) {
    // ---- phase 0: av + bv(n0-3), stage A(T+2), 16 MFMA ----
    bf16x8 av[4], bv[4];
#pragma unroll
    for (int i = 0; i < 4; ++i) av[i] = ldswz(pc, wm + i * 16 + frow);
#pragma unroll
    for (int j = 0; j < 4; ++j) bv[j] = ldswz(pc + 4096, wn + j * 16 + frow);
    if (T + 2 < nt) stageA(pf, (T + 2) * 32);
    S_BARRIER();
    LGKM0();
    __builtin_amdgcn_s_setprio(1);
#pragma unroll
    for (int i = 0; i < 4; ++i)
#pragma unroll
      for (int j = 0; j < 4; ++j)
        acc[i][j] = __builtin_amdgcn_mfma_f32_16x16x32_bf16(av[i], bv[j], acc[i][j], 0, 0, 0);
    __builtin_amdgcn_s_setprio(0);
    // ---- phase 1: bv(n4-7), stage B(T+2), VM gate, 16 MFMA ----
    bf16x8 b2[4];
#pragma unroll
    for (int j = 0; j < 4; ++j) b2[j] = ldswz(pc + 4096, wn + 64 + j * 16 + frow);
    if (T + 2 < nt) {
      stageB(pf, (T + 2) * 32);
      if (T + 1 < nt) asm volatile("s_waitcnt vmcnt(6)" ::: "memory");
    } else if (T + 1 < nt) {
      asm volatile("s_waitcnt vmcnt(0)" ::: "memory");
    }
    S_BARRIER();
    LGKM0();
    __builtin_amdgcn_s_setprio(1);
#pragma unroll
    for (int i = 0; i < 4; ++i)
#pragma unroll
      for (int j = 0; j < 4; ++j)
        acc[i][4 + j] = __builtin_amdgcn_mfma_f32_16x16x32_bf16(av[i], b2[j], acc[i][4 + j], 0, 0, 0);
    __builtin_amdgcn_s_setprio(0);
    unsigned short* t = pc; pc = pn; pn = pf; pf = t;
  }

  const int cr = (lane >> 4) * 4;
  const int cc = lane & 15;
#pragma unroll
  for (int mf = 0; mf < 4; ++mf) {
    const int r0 = tm + wm + mf * 16 + cr;
#pragma unroll
    for (int j = 0; j < 8; ++j) {
      const int col = tn + wn + j * 16 + cc;
#pragma unroll
      for (int i = 0; i < 4; ++i) {
        if (F32) ((float*)C)[(long long)(r0 + i) * ldc + col] = acc[mf][j][i];
        else ((unsigned short*)C)[(long long)(r0 + i) * ldc + col] = f2bf(acc[mf][j][i]);
      }
    }
  }
}

// Batched (z = group) two-segment GEMM, bf16 output. XCD-swizzled tiles.
__global__ __launch_bounds__(256, 2) void gemm4(
    const unsigned short* __restrict__ A1, int lda1, long long a1_bs, int K1,
    const unsigned short* __restrict__ A2, int lda2, int K2,
    const unsigned short* __restrict__ Bt, int ldb, long long bt_bs,
    unsigned short* __restrict__ C, int ldc, long long c_bs)
{
  __shared__ unsigned short lds[3 * 12288];   // 72 KB
  int tx, ty, g;
  xcd_tile(tx, ty, g);
  gemm4_core<0>(A1 + (long long)g * a1_bs, lda1, K1, A2, lda2, K2,
                Bt + (long long)g * bt_bs, ldb,
                C + (long long)g * c_bs, ldc,
                ty * 128, tx * 256, lds);
}

// Branch pack: z selects one of 8 configs (7x split-K of branch0 + branch1).
struct BCfg { const unsigned short* A; int lda; int K;
              const unsigned short* Bt; int ldb; unsigned short* C; };
struct BPack { BCfg c[8]; };
__global__ __launch_bounds__(256, 2) void gemm4_branch(BPack p) {
  __shared__ unsigned short lds[3 * 12288];
  int tx, ty, z;
  xcd_tile(tx, ty, z);
  BCfg c = p.c[z];
  gemm4_core<0>(c.A, c.lda, c.K, nullptr, 0, 0, c.Bt, c.ldb, c.C, 512,
                ty * 128, tx * 256, lds);
}

// ---------------------------------------------------------------------------
// Fused gates GEMM + GRU combine, v7 2-blocks/CU partitioning.
// Tile 128M x 192N(nn), 4 waves (2M x 2N), wave = 64 x 96 (2 gate-stripes).
// Buffer 20KB: A 128x32 @0 (8KB), B 192x32 @8192 (12KB); 3 bufs = 60KB.
// Stage loads/thread/step: A 2 + B 3 = 5 -> steady vmcnt(5).
// ---------------------------------------------------------------------------
__global__ __launch_bounds__(256, 2) void gemm_gru(
    const unsigned short* __restrict__ hB,
    const unsigned short* __restrict__ Wgt,
    const float* __restrict__ bg,
    const unsigned short* __restrict__ deterB,
    float* __restrict__ out)
{
  __shared__ unsigned short lds[3 * 10240];   // 60 KB
  int txi, tyi, g;
  xcd_tile(txi, tyi, g);
  const int tm = tyi * 128;
  const int tn = txi * 192;
  const unsigned short* A  = hB + g * 512;
  const unsigned short* Bt = Wgt + (long long)g * 1536 * 512;
  const int tid = threadIdx.x, lane = tid & 63, wave = tid >> 6;
  const int wm = (wave >> 1) * 64;
  const int wn = (wave & 1) * 96;
  const int frow = lane & 15, chunk16 = (lane >> 4) * 16;
  const int nt = 16;                          // K=512

  auto stageA = [&](unsigned short* buf, int kt) {
#pragma unroll
    for (int j = 0; j < 2; ++j) {
      int o = j * 4096 + tid * 16;
      int so = o ^ (((o >> 7) & 3) << 4);
      int row = so >> 6, cb = so & 63;
      GLOAD_LDS16(A + (long long)(tm + row) * 4096 + kt + (cb >> 1),
                  (char*)buf + j * 4096 + wave * 1024);
    }
  };
  auto stageB = [&](unsigned short* buf, int kt) {
    char* bb = (char*)buf + 8192;
#pragma unroll
    for (int j = 0; j < 3; ++j) {
      int o = j * 4096 + tid * 16;
      int so = o ^ (((o >> 7) & 3) << 4);
      int row = so >> 6, cb = so & 63;
      GLOAD_LDS16(Bt + (long long)(tn + row) * 512 + kt + (cb >> 1),
                  bb + j * 4096 + wave * 1024);
    }
  };
  auto ldA = [&](const unsigned short* buf, int row) -> bf16x8 {
    int o = row * 64 + chunk16; o ^= ((o >> 7) & 3) << 4;
    return *(const bf16x8*)((const char*)buf + o);
  };
  auto ldB = [&](const unsigned short* buf, int nf) -> bf16x8 {
    int row = wn + nf * 16 + frow;
    int o = row * 64 + chunk16; o ^= ((o >> 7) & 3) << 4;
    return *(const bf16x8*)((const char*)buf + 8192 + o);
  };

  f32x4 acc[4][6] = {};

  unsigned short* pc = lds;
  unsigned short* pn = lds + 10240;
  unsigned short* pf = lds + 20480;

  stageA(pc, 0); stageB(pc, 0);
  stageA(pn, 32); stageB(pn, 32);
  asm volatile("s_waitcnt vmcnt(5)" ::: "memory");
  S_BARRIER();

  for (int T = 0; T < nt; ++T) {
    // phase 0: av + bv(nf 0-2), stage A(T+2), 12 MFMA
    bf16x8 av[4], bv[3];
#pragma unroll
    for (int i = 0; i < 4; ++i) av[i] = ldA(pc, wm + i * 16 + frow);
#pragma unroll
    for (int j = 0; j < 3; ++j) bv[j] = ldB(pc, j);
    if (T + 2 < nt) stageA(pf, (T + 2) * 32);
    S_BARRIER();
    LGKM0();
    __builtin_amdgcn_s_setprio(1);
#pragma unroll
    for (int i = 0; i < 4; ++i)
#pragma unroll
      for (int j = 0; j < 3; ++j)
        acc[i][j] = __builtin_amdgcn_mfma_f32_16x16x32_bf16(av[i], bv[j], acc[i][j], 0, 0, 0);
    __builtin_amdgcn_s_setprio(0);
    // phase 1: bv(nf 3-5), stage B(T+2), VM gate, 12 MFMA
    bf16x8 b2[3];
#pragma unroll
    for (int j = 0; j < 3; ++j) b2[j] = ldB(pc, 3 + j);
    if (T + 2 < nt) {
      stageB(pf, (T + 2) * 32);
      if (T + 1 < nt) asm volatile("s_waitcnt vmcnt(5)" ::: "memory");
    } else if (T + 1 < nt) {
      asm volatile("s_waitcnt vmcnt(0)" ::: "memory");
    }
    S_BARRIER();
    LGKM0();
    __builtin_amdgcn_s_setprio(1);
#pragma unroll
    for (int i = 0; i < 4; ++i)
#pragma unroll
      for (int j = 0; j < 3; ++j)
        acc[i][3 + j] = __builtin_amdgcn_mfma_f32_16x16x32_bf16(av[i], b2[j], acc[i][3 + j], 0, 0, 0);
    __builtin_amdgcn_s_setprio(0);
    unsigned short* t = pc; pc = pn; pn = pf; pf = t;
  }

  // GRU epilogue: nf = ob*3 + gate; o_col block base = txi*64
  const int cr = (lane >> 4) * 4, cc = lane & 15;
#pragma unroll
  for (int ob = 0; ob < 2; ++ob) {
    const int o_col = (txi * 4 + (wave & 1) * 2 + ob) * 16 + cc;
    const int gcol = g * 512 + o_col;
    const float bgr = bg[g * 1536 + o_col];
    const float bgc = bg[g * 1536 + 512 + o_col];
    const float bgu = bg[g * 1536 + 1024 + o_col];
#pragma unroll
    for (int mf = 0; mf < 4; ++mf) {
      const int r0 = tm + wm + mf * 16 + cr;
#pragma unroll
      for (int i = 0; i < 4; ++i) {
        const long long off = (long long)(r0 + i) * 4096 + gcol;
        float dt = bf2f(deterB[off]);
        float reset = sigmoid_fast(acc[mf][ob * 3 + 0][i] + bgr);
        float cand  = tanh_fast(reset * (acc[mf][ob * 3 + 1][i] + bgc));
        float upd   = sigmoid_fast(acc[mf][ob * 3 + 2][i] + bgu - 1.f);
        out[off] = upd * cand + (1.f - upd) * dt;
      }
    }
  }
}

// ---------------------------------------------------------------------------
// Merged preprocessing: fp32->bf16 casts + all weight transposes, one launch.
// ---------------------------------------------------------------------------
__device__ __forceinline__ void transpose_dev(
    const float* __restrict__ src, unsigned short* __restrict__ dst,
    int R, int C, int bx, int by, int bz, float (*t)[132])
{
  const long long bOff = (long long)bz * R * C;
  src += bOff; dst += bOff;
  const int c0 = bx * 128, r0 = by * 32;
  const int tid = threadIdx.x;
  const int tx = tid & 31, ty = tid >> 5;
#pragma unroll
  for (int j = 0; j < 4; ++j) {
    int row = ty + j * 8;
    float4 v = *(const float4*)&src[(long long)(r0 + row) * C + c0 + tx * 4];
    *(float4*)&t[row][tx * 4] = v;
  }
  __syncthreads();
#pragma unroll
  for (int j = 0; j < 4; ++j) {
    int idx = j * 256 + tid;
    int c = idx >> 3, rg = idx & 7;
    u16x4 o;
    o.x = f2bf(t[rg * 4 + 0][c]); o.y = f2bf(t[rg * 4 + 1][c]);
    o.z = f2bf(t[rg * 4 + 2][c]); o.w = f2bf(t[rg * 4 + 3][c]);
    *(u16x4*)&dst[(long long)(c0 + c) * R + r0 + rg * 4] = o;
  }
}

__device__ __forceinline__ void transpose_wg_dev(
    const float* __restrict__ src, unsigned short* __restrict__ dst,
    int bx, int by, int bz, float (*t)[132])
{
  src += (long long)bz * 512 * 1536;
  dst += (long long)bz * 1536 * 512;
  const int c0 = bx * 128, r0 = by * 32;
  const int tid = threadIdx.x;
  const int tx = tid & 31, ty = tid >> 5;
#pragma unroll
  for (int j = 0; j < 4; ++j) {
    int row = ty + j * 8;
    float4 v = *(const float4*)&src[(long long)(r0 + row) * 1536 + c0 + tx * 4];
    *(float4*)&t[row][tx * 4] = v;
  }
  __syncthreads();
#pragma unroll
  for (int j = 0; j < 4; ++j) {
    int idx = j * 256 + tid;
    int c = idx >> 3, rg = idx & 7;
    int cc = c0 + c;
    int gate = cc >> 9, o = cc & 511;
    int nn = (o >> 4) * 48 + gate * 16 + (o & 15);
    u16x4 oo;
    oo.x = f2bf(t[rg * 4 + 0][c]); oo.y = f2bf(t[rg * 4 + 1][c]);
    oo.z = f2bf(t[rg * 4 + 2][c]); oo.w = f2bf(t[rg * 4 + 3][c]);
    *(u16x4*)&dst[(long long)nn * 512 + r0 + rg * 4] = oo;
  }
}

__global__ __launch_bounds__(256) void preproc_k(
    const float* __restrict__ deter, unsigned short* __restrict__ deterB,
    const float* __restrict__ stoch, unsigned short* __restrict__ stochB,
    const float* __restrict__ W0, unsigned short* __restrict__ W0t,
    const float* __restrict__ W1, unsigned short* __restrict__ W1t,
    const float* __restrict__ Wh0, unsigned short* __restrict__ Wh0t,
    const float* __restrict__ Wh1, unsigned short* __restrict__ Wh1t,
    const float* __restrict__ Wg, unsigned short* __restrict__ Wgt)
{
  __shared__ float t[32][132];
  int b = blockIdx.x;
  if (b < 20480) {
    int i = b * 256 + threadIdx.x;
    const float* s; unsigned short* d;
    if (i < 4194304) { s = deter; d = deterB; }
    else { i -= 4194304; if (i >= 1048576) return; s = stoch; d = stochB; }
    float4 v = ((const float4*)s)[i];
    u16x4 o;
    o.x = f2bf(v.x); o.y = f2bf(v.y); o.z = f2bf(v.z); o.w = f2bf(v.w);
    ((u16x4*)d)[i] = o;
    return;
  }
  b -= 20480;
  if (b < 512)  { transpose_dev(W0, W0t, 4096, 512, b & 3, b >> 2, 0, t); return; }
  b -= 512;
  if (b < 128)  { transpose_dev(W1, W1t, 1024, 512, b & 3, b >> 2, 0, t); return; }
  b -= 128;
  if (b < 2560) { transpose_dev(Wh0, Wh0t, 2560, 512, b & 3, (b >> 2) % 80, b / 320, t); return; }
  b -= 2560;
  if (b < 512)  { transpose_dev(Wh1, Wh1t, 512, 512, b & 3, (b >> 2) & 15, b >> 6, t); return; }
  b -= 512;
  transpose_wg_dev(Wg, Wgt, b % 12, (b / 12) & 15, b / 192, t);
}

// ---------------------------------------------------------------------------
// Merged branch epilogues. blockIdx.y: 0 -> branch0 (sum 7 bf16 split-K
// partials), 1 -> branch1, 2/3 -> branch2/3 (tiny-K fp32 GEMM).
// All: +bias -> RMSNorm(512) -> SiLU -> x (bf16).
// ---------------------------------------------------------------------------
__global__ __launch_bounds__(256) void branch_epi_k(
    const unsigned short* __restrict__ yP0b, const unsigned short* __restrict__ yP1b,
    const float* __restrict__ b0, const float* __restrict__ g0,
    const float* __restrict__ b1, const float* __restrict__ g1,
    const float* __restrict__ action, const float* __restrict__ demb,
    const float* __restrict__ W2, const float* __restrict__ b2, const float* __restrict__ g2,
    const float* __restrict__ W3, const float* __restrict__ b3, const float* __restrict__ g3,
    unsigned short* __restrict__ x)
{
  const int row = blockIdx.x, br = blockIdx.y;
  const int tid = threadIdx.x, lane = tid & 63, wave = tid >> 6;
  __shared__ float red[4];
  __shared__ float a[32];
  float v0, v1;
  const float* gg;
  if (br == 0) {
    const unsigned short* p = yP0b + (long long)row * 512;
    v0 = b0[tid]; v1 = b0[tid + 256];
#pragma unroll
    for (int c = 0; c < 7; ++c) {
      v0 += bf2f(p[(long long)c * 2097152 + tid]);
      v1 += bf2f(p[(long long)c * 2097152 + tid + 256]);
    }
    gg = g0;
  } else if (br == 1) {
    const unsigned short* p = yP1b + (long long)row * 512;
    v0 = b1[tid] + bf2f(p[tid]);
    v1 = b1[tid + 256] + bf2f(p[tid + 256]);
    gg = g1;
  } else {
    const int K = (br == 3) ? 16 : 32;
    const float* W  = (br == 3) ? W3 : W2;
    const float* bb = (br == 3) ? b3 : b2;
    gg = (br == 3) ? g3 : g2;
    if (tid < K) {
      float t = (br == 3) ? demb[(long long)row * 16 + tid]
                          : action[(long long)row * 32 + tid];
      if (br == 2) t = t / fmaxf(fabsf(t), 1.f);
      a[tid] = t;
    }
    __syncthreads();
    v0 = bb[tid]; v1 = bb[tid + 256];
    for (int k = 0; k < K; ++k) {
      float av = a[k];
      v0 += av * W[k * 512 + tid];
      v1 += av * W[k * 512 + tid + 256];
    }
  }
  float ss = v0 * v0 + v1 * v1;
  for (int o = 32; o > 0; o >>= 1) ss += __shfl_xor(ss, o);
  if (lane == 0) red[wave] = ss;
  __syncthreads();
  float ms = (red[0] + red[1] + red[2] + red[3]) * (1.f / 512.f);
  float sc = rsqrtf(ms + 1e-4f);
  unsigned short* xr = x + (long long)row * 2048 + br * 512;
  xr[tid]       = f2bf(siluf_(v0 * sc * gg[tid]));
  xr[tid + 256] = f2bf(siluf_(v1 * sc * gg[tid + 256]));
}

// ---------------------------------------------------------------------------
// Full-width (4096) epilogue: y(bf16) + bias -> RMSNorm -> SiLU -> h(bf16).
// ---------------------------------------------------------------------------
__global__ __launch_bounds__(256) void epi_full_k(
    const unsigned short* __restrict__ y, const float* __restrict__ bias,
    const float* __restrict__ gw, unsigned short* __restrict__ h)
{
  const int row = blockIdx.x;
  __shared__ float red[4];
  const int tid = threadIdx.x, lane = tid & 63, wave = tid >> 6;
  const u16x8* yv = (const u16x8*)(y + (long long)row * 4096);
  u16x8 ta = yv[tid], tb = yv[256 + tid];
  float ba[8], bb8[8];
  *(float4*)&ba[0]  = *(const float4*)&bias[tid * 8];
  *(float4*)&ba[4]  = *(const float4*)&bias[tid * 8 + 4];
  *(float4*)&bb8[0] = *(const float4*)&bias[(256 + tid) * 8];
  *(float4*)&bb8[4] = *(const float4*)&bias[(256 + tid) * 8 + 4];
  float fa[8], fb[8];
  float ss = 0.f;
#pragma unroll
  for (int e = 0; e < 8; ++e) {
    fa[e] = bf2f(ta[e]) + ba[e];  ss += fa[e] * fa[e];
    fb[e] = bf2f(tb[e]) + bb8[e]; ss += fb[e] * fb[e];
  }
  for (int o = 32; o > 0; o >>= 1) ss += __shfl_xor(ss, o);
  if (lane == 0) red[wave] = ss;
  __syncthreads();
  float ms = (red[0] + red[1] + red[2] + red[3]) * (1.f / 4096.f);
  float sc = rsqrtf(ms + 1e-4f);
  float ga[8], gb8[8];
  *(float4*)&ga[0]  = *(const float4*)&gw[tid * 8];
  *(float4*)&ga[4]  = *(const float4*)&gw[tid * 8 + 4];
  *(float4*)&gb8[0] = *(const float4*)&gw[(256 + tid) * 8];
  *(float4*)&gb8[4] = *(const float4*)&gw[(256 + tid) * 8 + 4];
  u16x8 oa, ob;
#pragma unroll
  for (int e = 0; e < 8; ++e) {
    oa[e] = f2bf(siluf_(fa[e] * sc * ga[e]));
    ob[e] = f2bf(siluf_(fb[e] * sc * gb8[e]));
  }
  u16x8* hv = (u16x8*)(h + (long long)row * 4096);
  hv[tid] = oa;
  hv[256 + tid] = ob;
}

// ---------------------------------------------------------------------------
extern "C" void kernel_launch(void* const* d_in, const int* in_sizes, int n_in,
                              void* d_out, int out_size, void* d_ws, size_t ws_size,
                              hipStream_t stream) {
  const float* stoch  = (const float*)d_in[0];
  const float* deter  = (const float*)d_in[1];
  const float* action = (const float*)d_in[2];
  const float* demb   = (const float*)d_in[3];
  const float* W0 = (const float*)d_in[4];
  const float* b0 = (const float*)d_in[5];
  const float* g0 = (const float*)d_in[6];
  const float* W1 = (const float*)d_in[7];
  const float* b1 = (const float*)d_in[8];
  const float* g1 = (const float*)d_in[9];
  const float* W2 = (const float*)d_in[10];
  const float* b2 = (const float*)d_in[11];
  const float* g2 = (const float*)d_in[12];
  const float* W3 = (const float*)d_in[13];
  const float* b3 = (const float*)d_in[14];
  const float* g3 = (const float*)d_in[15];
  const float* Wh0 = (const float*)d_in[16];
  const float* bh0 = (const float*)d_in[17];
  const float* gh0 = (const float*)d_in[18];
  const float* Wh1 = (const float*)d_in[19];
  const float* bh1 = (const float*)d_in[20];
  const float* gh1 = (const float*)d_in[21];
  const float* Wg  = (const float*)d_in[22];
  const float* bg  = (const float*)d_in[23];
  float* out = (float*)d_out;

  char* ws = (char*)d_ws;
  unsigned short* deterB = (unsigned short*)(ws + 0);          // 33.55 MB, whole run
  unsigned short* stochB = (unsigned short*)(ws + 33554432);   //  8.39 MB
  unsigned short* W0t    = (unsigned short*)(ws + 41943040);   //  4.19 MB
  unsigned short* W1t    = (unsigned short*)(ws + 46137344);   //  1.05 MB
  unsigned short* xB     = (unsigned short*)(ws + 47185920);   // 16.78 MB
  unsigned short* yP0b   = (unsigned short*)(ws + 63963136);   // 29.36 MB: 7 bf16 partials (early)
  unsigned short* yB     = (unsigned short*)(ws + 63963136);   // 33.55 MB (late)
  unsigned short* yP1b   = (unsigned short*)(ws + 97517568);   //  4.19 MB bf16 partial
  unsigned short* Wh0t   = (unsigned short*)(ws + 105906176);  // 20.97 MB
  unsigned short* Wh1t   = (unsigned short*)(ws + 126877696);  //  4.19 MB
  unsigned short* hB     = (unsigned short*)(ws + 134217728);  // 33.55 MB
  unsigned short* Wgt    = (unsigned short*)(ws + 167772160);  // 12.58 MB -> ends 180.4 MB
  (void)in_sizes; (void)n_in; (void)out_size; (void)ws_size;

  dim3 b256(256);
  // all preprocessing in one launch (casts + 5 transposes)
  preproc_k<<<dim3(25728), b256, 0, stream>>>(deter, deterB, stoch, stochB,
                                              W0, W0t, W1, W1t, Wh0, Wh0t,
                                              Wh1, Wh1t, Wg, Wgt);
  // branches 0+1: split-K x7 for branch0 (640 + 6x576) + branch1 (K=1024).
  // Grid 512 wg = exactly 2 blocks/CU, single round.
  {
    const int k0s[7]  = {0, 640, 1216, 1792, 2368, 2944, 3520};
    const int klen[7] = {640, 576, 576, 576, 576, 576, 576};
    BPack p;
    for (int z = 0; z < 7; ++z)
      p.c[z] = { deterB + k0s[z], 4096, klen[z], W0t + k0s[z], 4096,
                 yP0b + (long long)z * 2097152 };
    p.c[7] = { stochB, 1024, 1024, W1t, 1024, yP1b };
    gemm4_branch<<<dim3(2, 32, 8), b256, 0, stream>>>(p);
  }
  // all four branch epilogues in one launch
  branch_epi_k<<<dim3(4096, 4), b256, 0, stream>>>(yP0b, yP1b, b0, g0, b1, g1,
                                                   action, demb, W2, b2, g2, W3, b3, g3, xB);
  // hidden block layer 0: [deter_blk | x] @ Wh0  (512 wg, single round)
  gemm4<<<dim3(2, 32, 8), b256, 0, stream>>>(deterB, 4096, 512, 512, xB, 2048, 2048,
                                             Wh0t, 2560, 512LL * 2560, yB, 4096, 512);
  epi_full_k<<<dim3(4096), b256, 0, stream>>>(yB, bh0, gh0, hB);
  // hidden block layer 1  (512 wg, single round)
  gemm4<<<dim3(2, 32, 8), b256, 0, stream>>>(hB, 4096, 512, 512, nullptr, 0, 0,
                                             Wh1t, 512, 512LL * 512, yB, 4096, 512);
  epi_full_k<<<dim3(4096), b256, 0, stream>>>(yB, bh1, gh1, hB);
  // fused gates GEMM + GRU combine -> out (fp32); 2048 wg = 4 exact rounds
  gemm_gru<<<dim3(8, 32, 8), b256, 0, stream>>>(hB, Wgt, bg, deterB, out);
}